// Round 5
// baseline (288.432 us; speedup 1.0000x reference)
//
#include <hip/hip_runtime.h>
#include <hip/hip_bf16.h>

// REGATConv on MI355X — round 12. 4-way replicated histogram counters.
//   ws: fcb bf16[256*256] | ftb bf16[N*256] | el[N*4] | er[N*4] | poffs[N+1]
//       | cursor int4[N] (4 replicas/node) | rkw int[E] | pk int[E + 7N + 64]
//   K1 init: fc_w->bf16 convert + zero cursor (int4 grid-stride)
//   K2 gemm_hist: heterogeneous grid, HIST BLOCKS FIRST (blockIdx < HB) so they
//      spread 1/CU before GEMM blocks pack the machine.
//      hist: r=i&3; rank=atomicAdd(&cursor[dst*4+r],1);
//            rkw=src|(et<<17)|(r<<20)|(rank<<22)   [4x less same-addr contention]
//      gemm: MFMA bf16 GEMM (64x256 tile, wave=head) + el/er epilogue.
//   K3 scan (single block): v[node]=sum of int4 replicas; poffs = excl prefix of
//      padded counts ((v+7)&~7)
//   K4 pack (no atomics): c4=cursor4[dst]; base=poffs[dst]+sum(c4[r'<r]);
//      pk[base+rank] = low 20 bits (src|et)
//   K5 agg4: one wave per dst; deg = sum(cursor4[node]); 8-wide padded groups,
//      masked last group, 1-ahead pk prefetch; fused-exp single pass.

#define NF 256
#define HD 256
#define NH 4

typedef __attribute__((ext_vector_type(8))) short short8;
typedef __attribute__((ext_vector_type(4))) float f32x4;

static __device__ __forceinline__ unsigned short f2bf(float f) {
  unsigned int u = __float_as_uint(f);
  u += 0x7FFFu + ((u >> 16) & 1u);   // RNE
  return (unsigned short)(u >> 16);
}
static __device__ __forceinline__ float bf2f(unsigned short s) {
  return __uint_as_float(((unsigned int)s) << 16);
}
static __device__ __forceinline__ unsigned pkbf(float a, float b) {
  __hip_bfloat162 h = __float22bfloat162_rn(make_float2(a, b));
  return *(unsigned*)&h;
}
static __device__ __forceinline__ float wcalc(float sum, float ew) {
  float x = sum * ew;
  x = (x >= 0.f) ? x : 0.2f * x;
  return __expf(x);
}

// K1: fc_w fp32->bf16 convert + zero cursor (N int4s). 64 blocks x 256.
__global__ __launch_bounds__(256) void init_k(
    const float* __restrict__ w, unsigned short* __restrict__ o,
    int4* __restrict__ cursor4, int n) {
  int i = blockIdx.x * 256 + threadIdx.x;
  if (i < 16384) {
    float4 v = ((const float4*)w)[i];
    ((uint2*)o)[i] = make_uint2(pkbf(v.x, v.y), pkbf(v.z, v.w));
  }
  for (int q = i; q < n; q += 64 * 256) cursor4[q] = make_int4(0, 0, 0, 0);
}

// K2: heterogeneous grid — hist blocks [0,hb) FIRST, gemm blocks [hb, hb+gb).
__global__ __launch_bounds__(256) void gemm_hist_k(
    const float* __restrict__ feat, const unsigned short* __restrict__ fcb,
    const float* __restrict__ attn_l, const float* __restrict__ attn_r,
    unsigned short* __restrict__ ftb, float* __restrict__ el,
    float* __restrict__ er, int n,
    const int* __restrict__ src, const int* __restrict__ dst,
    const int* __restrict__ efeats, int* __restrict__ cursor,
    unsigned* __restrict__ rkw, int e, int hb) {
  __shared__ short aF[4 * 2 * 64 * 8];    // [rt][s][lane][8]  8 KB
  __shared__ short bF[16 * 2 * 64 * 8];   // [cg][s][lane][8] 32 KB

  if (blockIdx.x < hb) {
    // ---- hist role: replicated-counter atomic rank pass
    int stride = hb * 256;
    for (int i = blockIdx.x * 256 + threadIdx.x; i < e; i += stride) {
      int d = dst[i];
      unsigned r = (unsigned)i & 3u;
      unsigned rk = (unsigned)atomicAdd(&cursor[((unsigned)d << 2) | r], 1);
      rkw[i] = (unsigned)src[i] | (((unsigned)efeats[i] - 1u) << 17) |
               (r << 20) | (rk << 22);
    }
    return;
  }

  int tid = threadIdx.x;
  int lane = tid & 63, w = tid >> 6;
  int row0 = (blockIdx.x - hb) * 64;

  f32x4 acc[4][4];
#pragma unroll
  for (int i = 0; i < 4; ++i)
#pragma unroll
    for (int j = 0; j < 4; ++j) acc[i][j] = (f32x4){0.f, 0.f, 0.f, 0.f};

  int ar = tid >> 2, ak = (tid & 3) << 4;
  int arow = row0 + ar; if (arow >= n) arow = n - 1;
  const float* ap = feat + (size_t)arow * NF + ak;
  int am = ar & 15, art = ar >> 4;
  int s0 = ak >> 5, q0 = (ak >> 3) & 3;
  int s1 = (ak + 8) >> 5, q1 = ((ak + 8) >> 3) & 3;
  short* aw0 = &aF[(((art * 2 + s0) * 64) + q0 * 16 + am) * 8];
  short* aw1 = &aF[(((art * 2 + s1) * 64) + q1 * 16 + am) * 8];

  const unsigned short* bp = fcb + (size_t)tid * NF;
  int bn = tid & 15, bcg = tid >> 4;

  for (int k0 = 0; k0 < NF; k0 += 64) {
    float4 f0 = *(const float4*)(ap + k0);
    float4 f1 = *(const float4*)(ap + k0 + 4);
    float4 f2 = *(const float4*)(ap + k0 + 8);
    float4 f3 = *(const float4*)(ap + k0 + 12);
    uint4 oa = make_uint4(pkbf(f0.x, f0.y), pkbf(f0.z, f0.w),
                          pkbf(f1.x, f1.y), pkbf(f1.z, f1.w));
    uint4 ob = make_uint4(pkbf(f2.x, f2.y), pkbf(f2.z, f2.w),
                          pkbf(f3.x, f3.y), pkbf(f3.z, f3.w));
    *(uint4*)aw0 = oa;
    *(uint4*)aw1 = ob;
#pragma unroll
    for (int o8 = 0; o8 < 8; ++o8) {
      short8 bv = *(const short8*)(bp + k0 + o8 * 8);
      int bs = o8 >> 2, bq = o8 & 3;
      *(short8*)&bF[(((bcg * 2 + bs) * 64) + bq * 16 + bn) * 8] = bv;
    }
    __syncthreads();
#pragma unroll
    for (int s = 0; s < 2; ++s) {
      short8 af[4], bfr[4];
#pragma unroll
      for (int rt = 0; rt < 4; ++rt)
        af[rt] = *(const short8*)&aF[(((rt * 2 + s) * 64) + lane) * 8];
#pragma unroll
      for (int ct = 0; ct < 4; ++ct)
        bfr[ct] = *(const short8*)&bF[((((w * 4 + ct) * 2 + s) * 64) + lane) * 8];
#pragma unroll
      for (int rt = 0; rt < 4; ++rt)
#pragma unroll
        for (int ct = 0; ct < 4; ++ct)
          acc[rt][ct] = __builtin_amdgcn_mfma_f32_16x16x32_bf16(
              af[rt], bfr[ct], acc[rt][ct], 0, 0, 0);
    }
    __syncthreads();
  }

  // epilogue: wave w == head w. C/D map: col = lane&15, row = (lane>>4)*4 + r.
  int ln = lane & 15, lq = lane >> 4;
  float al4[4], ar4[4];
#pragma unroll
  for (int ct = 0; ct < 4; ++ct) {
    al4[ct] = attn_l[w * 64 + ct * 16 + ln];
    ar4[ct] = attn_r[w * 64 + ct * 16 + ln];
  }
#pragma unroll
  for (int rt = 0; rt < 4; ++rt) {
#pragma unroll
    for (int r = 0; r < 4; ++r) {
      float pl = 0.f, pr = 0.f;
#pragma unroll
      for (int ct = 0; ct < 4; ++ct) {
        float v = acc[rt][ct][r];
        pl += v * al4[ct]; pr += v * ar4[ct];
      }
#pragma unroll
      for (int off = 1; off <= 8; off <<= 1) {
        pl += __shfl_xor(pl, off);
        pr += __shfl_xor(pr, off);
      }
      int row = row0 + rt * 16 + lq * 4 + r;
      if (row < n) {
        if (ln == 0) { el[row * NH + w] = pl; er[row * NH + w] = pr; }
        unsigned short* fr = ftb + (size_t)row * HD + w * 64 + ln;
#pragma unroll
        for (int ct = 0; ct < 4; ++ct) fr[ct * 16] = f2bf(acc[rt][ct][r]);
      }
    }
  }
}

// K3: single-block scan. node count = sum of int4 replicas; prefix of PADDED
// counts ((v+7)&~7). 1024 thr x 8 nodes -> chunk 8192.
__global__ __launch_bounds__(1024) void scan_k(const int4* __restrict__ cursor4,
                                               int* __restrict__ poffs, int n) {
  __shared__ int wtot[16];
  __shared__ int wexcl[16];
  __shared__ int ctot;
  int tid = threadIdx.x, lane = tid & 63, wid = tid >> 6;
  int carry = 0;
  int nchunk = (n + 8191) >> 13;
  for (int c = 0; c < nchunk; ++c) {
    int base = (c << 13) + tid * 8;
    int v[8];
#pragma unroll
    for (int j = 0; j < 8; ++j) {
      int i = base + j;
      if (i < n) {
        int4 c4 = cursor4[i];
        v[j] = c4.x + c4.y + c4.z + c4.w;
      } else v[j] = 0;
    }
#pragma unroll
    for (int j = 0; j < 8; ++j) v[j] = (v[j] + 7) & ~7;   // pad to multiple of 8
    int p[8]; int run = 0;
#pragma unroll
    for (int j = 0; j < 8; ++j) { run += v[j]; p[j] = run; }
    int incl = run;
#pragma unroll
    for (int off = 1; off < 64; off <<= 1) {
      int t = __shfl_up(incl, off);
      if (lane >= off) incl += t;
    }
    if (lane == 63) wtot[wid] = incl;
    __syncthreads();
    if (wid == 0 && lane < 16) {
      int wv = wtot[lane]; int wi = wv;
#pragma unroll
      for (int off = 1; off < 16; off <<= 1) {
        int t = __shfl_up(wi, off);
        if (lane >= off) wi += t;
      }
      wexcl[lane] = wi - wv;
      if (lane == 15) ctot = wi;
    }
    __syncthreads();
    int ebase = carry + wexcl[wid] + (incl - run);
#pragma unroll
    for (int j = 0; j < 8; ++j) {
      int i = base + j;
      if (i < n) poffs[i] = ebase + p[j] - v[j];
    }
    carry += ctot;
    __syncthreads();
  }
  if (tid == 0) poffs[n] = carry;
}

// K4: group edges by dst (NO atomics).
// slot = poffs[d] + sum(cnt[r'<r]) + rank; pk[slot] = src|et (bits 0..19)
__global__ __launch_bounds__(256) void pack_k(
    const int* __restrict__ dst, const unsigned* __restrict__ rkw,
    const int* __restrict__ poffs, const int4* __restrict__ cursor4,
    int* __restrict__ pk, int e) {
  int i = blockIdx.x * 256 + threadIdx.x;
  if (i >= e) return;
  unsigned v = rkw[i];
  int d = dst[i];
  unsigned r = (v >> 20) & 3u;
  unsigned rk = v >> 22;
  int4 c4 = cursor4[d];
  int base = poffs[d] + ((r > 0) ? c4.x : 0) + ((r > 1) ? c4.y : 0) +
             ((r > 2) ? c4.z : 0);
  pk[base + (int)rk] = (int)(v & 0xFFFFFu);
}

// K5: one wave per dst node; lane owns output cols lane*4..lane*4+3 (head
// hl=lane>>4). All groups 8-wide (padded layout); last group sanitized via
// uniform-branch cndmasks; 1-ahead pk prefetch hides pk latency.
__global__ __launch_bounds__(256) void agg4_k(
    const unsigned short* __restrict__ ftb, const int* __restrict__ pk,
    const float* __restrict__ el, const float* __restrict__ er,
    const float* __restrict__ ewt, const int* __restrict__ poffs,
    const int4* __restrict__ cursor4, float* __restrict__ out, int n) {
  __shared__ float ew_s[32];
  if (threadIdx.x < 32) {
    float v = ewt[threadIdx.x] * 100.0f;
    ew_s[threadIdx.x] = (v >= 0.f) ? v : 0.01f * v;
  }
  __syncthreads();
  int node = blockIdx.x * 4 + (threadIdx.x >> 6);
  int lane = threadIdx.x & 63;
  if (node >= n) return;
  int start = poffs[node];
  int4 c4 = cursor4[node];
  int deg = c4.x + c4.y + c4.z + c4.w;
  float o0 = 0.f, o1 = 0.f, o2 = 0.f, o3 = 0.f;
  if (deg > 0) {
    int hl = lane >> 4;
    float er_h = er[(size_t)node * NH + hl];
    const unsigned short* fb = ftb + (size_t)lane * 4;
    const float* elh = el + hl;
    const int* pg = pk + start;
    float ss = 0.f;
    int ng = (deg + 7) >> 3;
    int4 pa = *(const int4*)(pg);
    int4 pb = *(const int4*)(pg + 4);
    for (int g = 0; g < ng; ++g) {
      // prefetch next group's pk (within padded region + slack; harmless)
      int4 na = *(const int4*)(pg + (g + 1) * 8);
      int4 nb = *(const int4*)(pg + (g + 1) * 8 + 4);
      int rem = deg - (g << 3);       // > 0; < 8 only possible on last group
      if (rem < 8) {                  // wave-uniform branch
        pa.y = (rem > 1) ? pa.y : 0;
        pa.z = (rem > 2) ? pa.z : 0;
        pa.w = (rem > 3) ? pa.w : 0;
        pb.x = (rem > 4) ? pb.x : 0;
        pb.y = (rem > 5) ? pb.y : 0;
        pb.z = (rem > 6) ? pb.z : 0;
        pb.w = (rem > 7) ? pb.w : 0;
      }
      int sA = pa.x & 0x1FFFF, tA = pa.x >> 17;
      int sB = pa.y & 0x1FFFF, tB = pa.y >> 17;
      int sC = pa.z & 0x1FFFF, tC = pa.z >> 17;
      int sD = pa.w & 0x1FFFF, tD = pa.w >> 17;
      int sE = pb.x & 0x1FFFF, tE = pb.x >> 17;
      int sF = pb.y & 0x1FFFF, tF = pb.y >> 17;
      int sG = pb.z & 0x1FFFF, tG = pb.z >> 17;
      int sH = pb.w & 0x1FFFF, tH = pb.w >> 17;
      float eA = elh[sA * NH], eB = elh[sB * NH], eC = elh[sC * NH], eD = elh[sD * NH];
      float eE = elh[sE * NH], eF = elh[sF * NH], eG = elh[sG * NH], eH = elh[sH * NH];
      ushort4 fA = *(const ushort4*)(fb + (size_t)sA * HD);
      ushort4 fB = *(const ushort4*)(fb + (size_t)sB * HD);
      ushort4 fC = *(const ushort4*)(fb + (size_t)sC * HD);
      ushort4 fD = *(const ushort4*)(fb + (size_t)sD * HD);
      ushort4 fE = *(const ushort4*)(fb + (size_t)sE * HD);
      ushort4 fF = *(const ushort4*)(fb + (size_t)sF * HD);
      ushort4 fG = *(const ushort4*)(fb + (size_t)sG * HD);
      ushort4 fH = *(const ushort4*)(fb + (size_t)sH * HD);
      float wA = wcalc(eA + er_h, ew_s[tA * NH + hl]);
      float wB = wcalc(eB + er_h, ew_s[tB * NH + hl]);
      float wC = wcalc(eC + er_h, ew_s[tC * NH + hl]);
      float wD = wcalc(eD + er_h, ew_s[tD * NH + hl]);
      float wE = wcalc(eE + er_h, ew_s[tE * NH + hl]);
      float wF = wcalc(eF + er_h, ew_s[tF * NH + hl]);
      float wG = wcalc(eG + er_h, ew_s[tG * NH + hl]);
      float wH = wcalc(eH + er_h, ew_s[tH * NH + hl]);
      if (rem < 8) {                  // zero weights of padded slots
        wB = (rem > 1) ? wB : 0.f;
        wC = (rem > 2) ? wC : 0.f;
        wD = (rem > 3) ? wD : 0.f;
        wE = (rem > 4) ? wE : 0.f;
        wF = (rem > 5) ? wF : 0.f;
        wG = (rem > 6) ? wG : 0.f;
        wH = (rem > 7) ? wH : 0.f;
      }
      ss += ((wA + wB) + (wC + wD)) + ((wE + wF) + (wG + wH));
      o0 = fmaf(wA, bf2f(fA.x), o0); o1 = fmaf(wA, bf2f(fA.y), o1);
      o2 = fmaf(wA, bf2f(fA.z), o2); o3 = fmaf(wA, bf2f(fA.w), o3);
      o0 = fmaf(wB, bf2f(fB.x), o0); o1 = fmaf(wB, bf2f(fB.y), o1);
      o2 = fmaf(wB, bf2f(fB.z), o2); o3 = fmaf(wB, bf2f(fB.w), o3);
      o0 = fmaf(wC, bf2f(fC.x), o0); o1 = fmaf(wC, bf2f(fC.y), o1);
      o2 = fmaf(wC, bf2f(fC.z), o2); o3 = fmaf(wC, bf2f(fC.w), o3);
      o0 = fmaf(wD, bf2f(fD.x), o0); o1 = fmaf(wD, bf2f(fD.y), o1);
      o2 = fmaf(wD, bf2f(fD.z), o2); o3 = fmaf(wD, bf2f(fD.w), o3);
      o0 = fmaf(wE, bf2f(fE.x), o0); o1 = fmaf(wE, bf2f(fE.y), o1);
      o2 = fmaf(wE, bf2f(fE.z), o2); o3 = fmaf(wE, bf2f(fE.w), o3);
      o0 = fmaf(wF, bf2f(fF.x), o0); o1 = fmaf(wF, bf2f(fF.y), o1);
      o2 = fmaf(wF, bf2f(fF.z), o2); o3 = fmaf(wF, bf2f(fF.w), o3);
      o0 = fmaf(wG, bf2f(fG.x), o0); o1 = fmaf(wG, bf2f(fG.y), o1);
      o2 = fmaf(wG, bf2f(fG.z), o2); o3 = fmaf(wG, bf2f(fG.w), o3);
      o0 = fmaf(wH, bf2f(fH.x), o0); o1 = fmaf(wH, bf2f(fH.y), o1);
      o2 = fmaf(wH, bf2f(fH.z), o2); o3 = fmaf(wH, bf2f(fH.w), o3);
      pa = na; pb = nb;
    }
    float rs = 1.0f / ss;
    o0 *= rs; o1 *= rs; o2 *= rs; o3 *= rs;
  }
  *(float4*)(out + (size_t)node * HD + lane * 4) = make_float4(o0, o1, o2, o3);
}

extern "C" void kernel_launch(void* const* d_in, const int* in_sizes, int n_in,
                              void* d_out, int out_size, void* d_ws, size_t ws_size,
                              hipStream_t stream) {
  const float* feat   = (const float*)d_in[0];
  const int*   src    = (const int*)d_in[1];
  const int*   dst    = (const int*)d_in[2];
  const int*   efeats = (const int*)d_in[3];
  const float* fc_w   = (const float*)d_in[4];
  const float* attn_l = (const float*)d_in[5];
  const float* attn_r = (const float*)d_in[6];
  const float* ewt    = (const float*)d_in[7];
  float* out = (float*)d_out;

  int N = in_sizes[0] / NF;   // 50000
  int E = in_sizes[1];        // 800000

  char* ws = (char*)d_ws;
  size_t off = 0;
  unsigned short* fcb = (unsigned short*)(ws + off); off += (size_t)NF * HD * 2;  // 128 KB
  unsigned short* ftb = (unsigned short*)(ws + off); off += (size_t)N * HD * 2;   // 25.6 MB
  float* el  = (float*)(ws + off);  off += (size_t)N * NH * 4;
  float* er  = (float*)(ws + off);  off += (size_t)N * NH * 4;
  int* poffs = (int*)(ws + off);    off += ((size_t)N + 16) * 4;
  int* cursor = (int*)(ws + off);   off += (size_t)N * 16;                         // 800 KB (int4/node)
  unsigned* rkw = (unsigned*)(ws + off); off += (size_t)E * 4;                     // 3.2 MB
  int* pk    = (int*)(ws + off);    off += ((size_t)E + 7 * (size_t)N + 64) * 4;  // ~4.6 MB

  int gblocks = (N + 63) / 64;               // 782 GEMM blocks
  int hblocks = 1024 - gblocks;              // 242 hist blocks, dispatched FIRST
  if (hblocks < 64) hblocks = 64;

  init_k<<<64, 256, 0, stream>>>(fc_w, fcb, (int4*)cursor, N);
  gemm_hist_k<<<gblocks + hblocks, 256, 0, stream>>>(
      feat, fcb, attn_l, attn_r, ftb, el, er, N,
      src, dst, efeats, cursor, rkw, E, hblocks);
  scan_k<<<1, 1024, 0, stream>>>((const int4*)cursor, poffs, N);
  pack_k<<<(E + 255) / 256, 256, 0, stream>>>(dst, rkw, poffs, (const int4*)cursor, pk, E);
  agg4_k<<<(N + 3) / 4, 256, 0, stream>>>(ftb, pk, el, er, ewt, poffs,
                                          (const int4*)cursor, out, N);
}

// Round 6
// 270.732 us; speedup vs baseline: 1.0654x; 1.0654x over previous
//
#include <hip/hip_runtime.h>
#include <hip/hip_bf16.h>

// REGATConv on MI355X — round 13. NO global atomics: 2-level LDS bucket sort.
//   ws: fcb bf16[256*256] | ftb bf16[N*256] | el[N*4] | er[N*4] | poffs[N+1]
//       | ghist int[65536] | sg int[65544] | mid int[E] | pk int[E]
//   K1 part_hist: 256 blocks; LDS 256-bin hist of dst>>8 -> ghist[bin][blk]
//      (+ fc_w->bf16 convert in blocks 0..63). LDS atomics only.
//   K2 scan2: single-block exclusive scan of ghist (65536) -> sg
//   K3 part_scatter: LDS cursors from sg; mid[pos] = src|et<<17|(dst&255)<<20
//      -> edges grouped into 196 buckets of 256 nodes
//   K4 bucket: 1 block/bucket: LDS hist of dst&255 -> wave0 scan -> poffs,
//      then LDS-cursor scatter -> pk (dst-grouped, 20-bit payload)
//   K5 gemm: MFMA bf16 GEMM (64x256 tile, wave=head) + fused el/er epilogue
//   K6 agg3: one wave per dst; 8-unrolled gather; fused-exp single pass.

#define NF 256
#define HD 256
#define NH 4
#define PB 256   // partition blocks

typedef __attribute__((ext_vector_type(8))) short short8;
typedef __attribute__((ext_vector_type(4))) float f32x4;

static __device__ __forceinline__ unsigned short f2bf(float f) {
  unsigned int u = __float_as_uint(f);
  u += 0x7FFFu + ((u >> 16) & 1u);   // RNE
  return (unsigned short)(u >> 16);
}
static __device__ __forceinline__ float bf2f(unsigned short s) {
  return __uint_as_float(((unsigned int)s) << 16);
}
static __device__ __forceinline__ unsigned pkbf(float a, float b) {
  __hip_bfloat162 h = __float22bfloat162_rn(make_float2(a, b));
  return *(unsigned*)&h;
}
static __device__ __forceinline__ float wcalc(float sum, float ew) {
  float x = sum * ew;
  x = (x >= 0.f) ? x : 0.2f * x;
  return __expf(x);
}

// K1: per-block 256-bin LDS histogram of dst>>8 (+ fc_w convert in blocks 0..63)
__global__ __launch_bounds__(256) void part_hist_k(
    const int* __restrict__ dst, const float* __restrict__ w,
    unsigned short* __restrict__ o, int* __restrict__ ghist, int e, int epb) {
  __shared__ int bins[256];
  int tid = threadIdx.x, blk = blockIdx.x;
  bins[tid] = 0;
  int ci = blk * 256 + tid;
  if (ci < 16384) {
    float4 v = ((const float4*)w)[ci];
    ((uint2*)o)[ci] = make_uint2(pkbf(v.x, v.y), pkbf(v.z, v.w));
  }
  __syncthreads();
  int e0 = blk * epb, e1 = e0 + epb; if (e1 > e) e1 = e;
  for (int i = e0 + tid; i < e1; i += 256)
    atomicAdd(&bins[dst[i] >> 8], 1);
  __syncthreads();
  ghist[tid * PB + blk] = bins[tid];
}

// K2: single-block exclusive scan (NO padding), 1024 thr x 8 -> chunk 8192
__global__ __launch_bounds__(1024) void scan2_k(const int* __restrict__ in,
                                                int* __restrict__ outp, int n) {
  __shared__ int wtot[16];
  __shared__ int wexcl[16];
  __shared__ int ctot;
  int tid = threadIdx.x, lane = tid & 63, wid = tid >> 6;
  int carry = 0;
  int nchunk = (n + 8191) >> 13;
  for (int c = 0; c < nchunk; ++c) {
    int base = (c << 13) + tid * 8;
    int v[8];
    if (base + 8 <= n) {
      int4 a = *(const int4*)(in + base);
      int4 b = *(const int4*)(in + base + 4);
      v[0] = a.x; v[1] = a.y; v[2] = a.z; v[3] = a.w;
      v[4] = b.x; v[5] = b.y; v[6] = b.z; v[7] = b.w;
    } else {
#pragma unroll
      for (int j = 0; j < 8; ++j) v[j] = (base + j < n) ? in[base + j] : 0;
    }
    int p[8]; int run = 0;
#pragma unroll
    for (int j = 0; j < 8; ++j) { run += v[j]; p[j] = run; }
    int incl = run;
#pragma unroll
    for (int off = 1; off < 64; off <<= 1) {
      int t = __shfl_up(incl, off);
      if (lane >= off) incl += t;
    }
    if (lane == 63) wtot[wid] = incl;
    __syncthreads();
    if (wid == 0 && lane < 16) {
      int wv = wtot[lane]; int wi = wv;
#pragma unroll
      for (int off = 1; off < 16; off <<= 1) {
        int t = __shfl_up(wi, off);
        if (lane >= off) wi += t;
      }
      wexcl[lane] = wi - wv;
      if (lane == 15) ctot = wi;
    }
    __syncthreads();
    int ebase = carry + wexcl[wid] + (incl - run);
#pragma unroll
    for (int j = 0; j < 8; ++j) {
      int i = base + j;
      if (i < n) outp[i] = ebase + p[j] - v[j];
    }
    carry += ctot;
    __syncthreads();
  }
  if (tid == 0) outp[n] = carry;
}

// K3: scatter edges into 256-node buckets via LDS cursors (no global atomics)
__global__ __launch_bounds__(256) void part_scatter_k(
    const int* __restrict__ src, const int* __restrict__ dst,
    const int* __restrict__ efeats, const int* __restrict__ sg,
    int* __restrict__ mid, int e, int epb) {
  __shared__ int cur[256];
  int tid = threadIdx.x, blk = blockIdx.x;
  cur[tid] = sg[tid * PB + blk];
  __syncthreads();
  int e0 = blk * epb, e1 = e0 + epb; if (e1 > e) e1 = e;
  for (int i = e0 + tid; i < e1; i += 256) {
    int d = dst[i];
    int pos = atomicAdd(&cur[d >> 8], 1);
    mid[pos] = src[i] | ((efeats[i] - 1) << 17) | ((d & 255) << 20);
  }
}

// K4: per-bucket (256 nodes) LDS counting-group: poffs + dst-grouped pk
__global__ __launch_bounds__(256) void bucket_k(
    const int* __restrict__ mid, const int* __restrict__ sg,
    int* __restrict__ poffs, int* __restrict__ pk, int nN) {
  __shared__ int cnt[256];
  __shared__ int cur[256];
  int tid = threadIdx.x, b = blockIdx.x;
  int bb0 = sg[b * PB];
  int bb1 = sg[(b + 1) * PB];
  cnt[tid] = 0;
  __syncthreads();
  for (int i = bb0 + tid; i < bb1; i += 256)
    atomicAdd(&cnt[(mid[i] >> 20) & 255], 1);
  __syncthreads();
  if (tid < 64) {
    int carry = 0;
#pragma unroll
    for (int c = 0; c < 4; ++c) {
      int v = cnt[c * 64 + tid];
      int inc = v;
#pragma unroll
      for (int off = 1; off < 64; off <<= 1) {
        int t2 = __shfl_up(inc, off);
        if (tid >= off) inc += t2;
      }
      cur[c * 64 + tid] = inc - v + carry;
      carry += __shfl(inc, 63);
    }
  }
  __syncthreads();
  int node = b * 256 + tid;
  int g = bb0 + cur[tid];
  if (node <= nN) poffs[node] = g;
  cur[tid] = g;
  __syncthreads();
  for (int i = bb0 + tid; i < bb1; i += 256) {
    int v = mid[i];
    int pos = atomicAdd(&cur[(v >> 20) & 255], 1);
    pk[pos] = v & 0xFFFFF;
  }
}

// K5: MFMA GEMM: C[m][o] = sum_k feat[m][k]*fc_w[o][k]. Block: 64 rows x 256
// cols, 4 waves; wave w owns cols [w*64, w*64+64) == head w. BK=64.
__global__ __launch_bounds__(256) void gemm_k(
    const float* __restrict__ feat, const unsigned short* __restrict__ fcb,
    const float* __restrict__ attn_l, const float* __restrict__ attn_r,
    unsigned short* __restrict__ ftb, float* __restrict__ el,
    float* __restrict__ er, int n) {
  __shared__ short aF[4 * 2 * 64 * 8];    // [rt][s][lane][8]  8 KB
  __shared__ short bF[16 * 2 * 64 * 8];   // [cg][s][lane][8] 32 KB
  int tid = threadIdx.x;
  int lane = tid & 63, w = tid >> 6;
  int row0 = blockIdx.x * 64;

  f32x4 acc[4][4];
#pragma unroll
  for (int i = 0; i < 4; ++i)
#pragma unroll
    for (int j = 0; j < 4; ++j) acc[i][j] = (f32x4){0.f, 0.f, 0.f, 0.f};

  int ar = tid >> 2, ak = (tid & 3) << 4;
  int arow = row0 + ar; if (arow >= n) arow = n - 1;
  const float* ap = feat + (size_t)arow * NF + ak;
  int am = ar & 15, art = ar >> 4;
  int s0 = ak >> 5, q0 = (ak >> 3) & 3;
  int s1 = (ak + 8) >> 5, q1 = ((ak + 8) >> 3) & 3;
  short* aw0 = &aF[(((art * 2 + s0) * 64) + q0 * 16 + am) * 8];
  short* aw1 = &aF[(((art * 2 + s1) * 64) + q1 * 16 + am) * 8];

  const unsigned short* bp = fcb + (size_t)tid * NF;
  int bn = tid & 15, bcg = tid >> 4;

  for (int k0 = 0; k0 < NF; k0 += 64) {
    float4 f0 = *(const float4*)(ap + k0);
    float4 f1 = *(const float4*)(ap + k0 + 4);
    float4 f2 = *(const float4*)(ap + k0 + 8);
    float4 f3 = *(const float4*)(ap + k0 + 12);
    uint4 oa = make_uint4(pkbf(f0.x, f0.y), pkbf(f0.z, f0.w),
                          pkbf(f1.x, f1.y), pkbf(f1.z, f1.w));
    uint4 ob = make_uint4(pkbf(f2.x, f2.y), pkbf(f2.z, f2.w),
                          pkbf(f3.x, f3.y), pkbf(f3.z, f3.w));
    *(uint4*)aw0 = oa;
    *(uint4*)aw1 = ob;
#pragma unroll
    for (int o8 = 0; o8 < 8; ++o8) {
      short8 bv = *(const short8*)(bp + k0 + o8 * 8);
      int bs = o8 >> 2, bq = o8 & 3;
      *(short8*)&bF[(((bcg * 2 + bs) * 64) + bq * 16 + bn) * 8] = bv;
    }
    __syncthreads();
#pragma unroll
    for (int s = 0; s < 2; ++s) {
      short8 af[4], bfr[4];
#pragma unroll
      for (int rt = 0; rt < 4; ++rt)
        af[rt] = *(const short8*)&aF[(((rt * 2 + s) * 64) + lane) * 8];
#pragma unroll
      for (int ct = 0; ct < 4; ++ct)
        bfr[ct] = *(const short8*)&bF[((((w * 4 + ct) * 2 + s) * 64) + lane) * 8];
#pragma unroll
      for (int rt = 0; rt < 4; ++rt)
#pragma unroll
        for (int ct = 0; ct < 4; ++ct)
          acc[rt][ct] = __builtin_amdgcn_mfma_f32_16x16x32_bf16(
              af[rt], bfr[ct], acc[rt][ct], 0, 0, 0);
    }
    __syncthreads();
  }

  // epilogue: wave w == head w. C/D map: col = lane&15, row = (lane>>4)*4 + r.
  int ln = lane & 15, lq = lane >> 4;
  float al4[4], ar4[4];
#pragma unroll
  for (int ct = 0; ct < 4; ++ct) {
    al4[ct] = attn_l[w * 64 + ct * 16 + ln];
    ar4[ct] = attn_r[w * 64 + ct * 16 + ln];
  }
#pragma unroll
  for (int rt = 0; rt < 4; ++rt) {
#pragma unroll
    for (int r = 0; r < 4; ++r) {
      float pl = 0.f, pr = 0.f;
#pragma unroll
      for (int ct = 0; ct < 4; ++ct) {
        float v = acc[rt][ct][r];
        pl += v * al4[ct]; pr += v * ar4[ct];
      }
#pragma unroll
      for (int off = 1; off <= 8; off <<= 1) {
        pl += __shfl_xor(pl, off);
        pr += __shfl_xor(pr, off);
      }
      int row = row0 + rt * 16 + lq * 4 + r;
      if (row < n) {
        if (ln == 0) { el[row * NH + w] = pl; er[row * NH + w] = pr; }
        unsigned short* fr = ftb + (size_t)row * HD + w * 64 + ln;
#pragma unroll
        for (int ct = 0; ct < 4; ++ct) fr[ct * 16] = f2bf(acc[rt][ct][r]);
      }
    }
  }
}

// K6: one wave per dst node; lane owns output cols lane*4..lane*4+3 (head
// hl=lane>>4). Single pass: w=exp(leaky((el+er)*ew)) inline; scale by 1/ss.
__global__ __launch_bounds__(256) void agg3_k(
    const unsigned short* __restrict__ ftb, const int* __restrict__ pk,
    const float* __restrict__ el, const float* __restrict__ er,
    const float* __restrict__ ewt, const int* __restrict__ offs,
    float* __restrict__ out, int n) {
  __shared__ float ew_s[32];
  if (threadIdx.x < 32) {
    float v = ewt[threadIdx.x] * 100.0f;
    ew_s[threadIdx.x] = (v >= 0.f) ? v : 0.01f * v;
  }
  __syncthreads();
  int node = blockIdx.x * 4 + (threadIdx.x >> 6);
  int lane = threadIdx.x & 63;
  if (node >= n) return;
  int start = offs[node];
  int deg = offs[node + 1] - start;
  float o0 = 0.f, o1 = 0.f, o2 = 0.f, o3 = 0.f;
  if (deg > 0) {
    int hl = lane >> 4;
    float er_h = er[(size_t)node * NH + hl];
    const unsigned short* fb = ftb + (size_t)lane * 4;
    const float* elh = el + hl;
    const int* pg = pk + start;
    float ss = 0.f;
    int i = 0;
    for (; i + 8 <= deg; i += 8) {
      int4 pa = *(const int4*)(pg + i);
      int4 pb = *(const int4*)(pg + i + 4);
      int sA = pa.x & 0x1FFFF, tA = pa.x >> 17;
      int sB = pa.y & 0x1FFFF, tB = pa.y >> 17;
      int sC = pa.z & 0x1FFFF, tC = pa.z >> 17;
      int sD = pa.w & 0x1FFFF, tD = pa.w >> 17;
      int sE = pb.x & 0x1FFFF, tE = pb.x >> 17;
      int sF = pb.y & 0x1FFFF, tF = pb.y >> 17;
      int sG = pb.z & 0x1FFFF, tG = pb.z >> 17;
      int sH = pb.w & 0x1FFFF, tH = pb.w >> 17;
      float eA = elh[sA * NH], eB = elh[sB * NH], eC = elh[sC * NH], eD = elh[sD * NH];
      float eE = elh[sE * NH], eF = elh[sF * NH], eG = elh[sG * NH], eH = elh[sH * NH];
      ushort4 fA = *(const ushort4*)(fb + (size_t)sA * HD);
      ushort4 fB = *(const ushort4*)(fb + (size_t)sB * HD);
      ushort4 fC = *(const ushort4*)(fb + (size_t)sC * HD);
      ushort4 fD = *(const ushort4*)(fb + (size_t)sD * HD);
      ushort4 fE = *(const ushort4*)(fb + (size_t)sE * HD);
      ushort4 fF = *(const ushort4*)(fb + (size_t)sF * HD);
      ushort4 fG = *(const ushort4*)(fb + (size_t)sG * HD);
      ushort4 fH = *(const ushort4*)(fb + (size_t)sH * HD);
      float wA = wcalc(eA + er_h, ew_s[tA * NH + hl]);
      float wB = wcalc(eB + er_h, ew_s[tB * NH + hl]);
      float wC = wcalc(eC + er_h, ew_s[tC * NH + hl]);
      float wD = wcalc(eD + er_h, ew_s[tD * NH + hl]);
      float wE = wcalc(eE + er_h, ew_s[tE * NH + hl]);
      float wF = wcalc(eF + er_h, ew_s[tF * NH + hl]);
      float wG = wcalc(eG + er_h, ew_s[tG * NH + hl]);
      float wH = wcalc(eH + er_h, ew_s[tH * NH + hl]);
      ss += ((wA + wB) + (wC + wD)) + ((wE + wF) + (wG + wH));
      o0 = fmaf(wA, bf2f(fA.x), o0); o1 = fmaf(wA, bf2f(fA.y), o1);
      o2 = fmaf(wA, bf2f(fA.z), o2); o3 = fmaf(wA, bf2f(fA.w), o3);
      o0 = fmaf(wB, bf2f(fB.x), o0); o1 = fmaf(wB, bf2f(fB.y), o1);
      o2 = fmaf(wB, bf2f(fB.z), o2); o3 = fmaf(wB, bf2f(fB.w), o3);
      o0 = fmaf(wC, bf2f(fC.x), o0); o1 = fmaf(wC, bf2f(fC.y), o1);
      o2 = fmaf(wC, bf2f(fC.z), o2); o3 = fmaf(wC, bf2f(fC.w), o3);
      o0 = fmaf(wD, bf2f(fD.x), o0); o1 = fmaf(wD, bf2f(fD.y), o1);
      o2 = fmaf(wD, bf2f(fD.z), o2); o3 = fmaf(wD, bf2f(fD.w), o3);
      o0 = fmaf(wE, bf2f(fE.x), o0); o1 = fmaf(wE, bf2f(fE.y), o1);
      o2 = fmaf(wE, bf2f(fE.z), o2); o3 = fmaf(wE, bf2f(fE.w), o3);
      o0 = fmaf(wF, bf2f(fF.x), o0); o1 = fmaf(wF, bf2f(fF.y), o1);
      o2 = fmaf(wF, bf2f(fF.z), o2); o3 = fmaf(wF, bf2f(fF.w), o3);
      o0 = fmaf(wG, bf2f(fG.x), o0); o1 = fmaf(wG, bf2f(fG.y), o1);
      o2 = fmaf(wG, bf2f(fG.z), o2); o3 = fmaf(wG, bf2f(fG.w), o3);
      o0 = fmaf(wH, bf2f(fH.x), o0); o1 = fmaf(wH, bf2f(fH.y), o1);
      o2 = fmaf(wH, bf2f(fH.z), o2); o3 = fmaf(wH, bf2f(fH.w), o3);
    }
    for (; i < deg; ++i) {
      int pv = pg[i];
      int sA = pv & 0x1FFFF, tA = pv >> 17;
      float eA = elh[sA * NH];
      ushort4 fA = *(const ushort4*)(fb + (size_t)sA * HD);
      float wA = wcalc(eA + er_h, ew_s[tA * NH + hl]);
      ss += wA;
      o0 = fmaf(wA, bf2f(fA.x), o0); o1 = fmaf(wA, bf2f(fA.y), o1);
      o2 = fmaf(wA, bf2f(fA.z), o2); o3 = fmaf(wA, bf2f(fA.w), o3);
    }
    float rs = 1.0f / ss;
    o0 *= rs; o1 *= rs; o2 *= rs; o3 *= rs;
  }
  *(float4*)(out + (size_t)node * HD + lane * 4) = make_float4(o0, o1, o2, o3);
}

extern "C" void kernel_launch(void* const* d_in, const int* in_sizes, int n_in,
                              void* d_out, int out_size, void* d_ws, size_t ws_size,
                              hipStream_t stream) {
  const float* feat   = (const float*)d_in[0];
  const int*   src    = (const int*)d_in[1];
  const int*   dst    = (const int*)d_in[2];
  const int*   efeats = (const int*)d_in[3];
  const float* fc_w   = (const float*)d_in[4];
  const float* attn_l = (const float*)d_in[5];
  const float* attn_r = (const float*)d_in[6];
  const float* ewt    = (const float*)d_in[7];
  float* out = (float*)d_out;

  int N = in_sizes[0] / NF;   // 50000
  int E = in_sizes[1];        // 800000

  char* ws = (char*)d_ws;
  size_t off = 0;
  unsigned short* fcb = (unsigned short*)(ws + off); off += (size_t)NF * HD * 2;  // 128 KB
  unsigned short* ftb = (unsigned short*)(ws + off); off += (size_t)N * HD * 2;   // 25.6 MB
  float* el  = (float*)(ws + off);  off += (size_t)N * NH * 4;
  float* er  = (float*)(ws + off);  off += (size_t)N * NH * 4;
  int* poffs = (int*)(ws + off);    off += ((size_t)N + 16) * 4;
  int* ghist = (int*)(ws + off);    off += (size_t)PB * 256 * 4;                  // 256 KB
  int* sg    = (int*)(ws + off);    off += ((size_t)PB * 256 + 8) * 4;            // 256 KB
  int* mid   = (int*)(ws + off);    off += (size_t)E * 4;                          // 3.2 MB
  int* pk    = (int*)(ws + off);    off += (size_t)E * 4;                          // 3.2 MB

  int epb = (E + PB - 1) / PB;       // 3125 edges per partition block
  int NB = (N >> 8) + 1;             // 196 buckets (256 nodes each)

  part_hist_k<<<PB, 256, 0, stream>>>(dst, fc_w, fcb, ghist, E, epb);
  scan2_k<<<1, 1024, 0, stream>>>(ghist, sg, PB * 256);
  part_scatter_k<<<PB, 256, 0, stream>>>(src, dst, efeats, sg, mid, E, epb);
  bucket_k<<<NB, 256, 0, stream>>>(mid, sg, poffs, pk, N);
  gemm_k<<<(N + 63) / 64, 256, 0, stream>>>(feat, fcb, attn_l, attn_r, ftb, el, er, N);
  agg3_k<<<(N + 3) / 4, 256, 0, stream>>>(ftb, pk, el, er, ewt, poffs, out, N);
}